// Round 1
// baseline (136.386 us; speedup 1.0000x reference)
//
#include <hip/hip_runtime.h>
#include <hip/hip_bf16.h>

#define HDIM 256
#define LDIM 384
#define BDIM 2
#define ADIM 14

// ---------------------------------------------------------------------------
// Kernel 1: one fused GEMM  C(768x512) = h(768x256) @ [Wx_w; Ux_w]^T + bias
// cols 0..255  -> hw[b][i][c]          (row-major, (B*L, H))
// cols 256..511-> huT[b][c-256][i]     (transposed so k_main's j-loads coalesce)
// ---------------------------------------------------------------------------
__global__ __launch_bounds__(256) void k_gemm(
    const float* __restrict__ h,
    const float* __restrict__ Wx_w, const float* __restrict__ Wx_b,
    const float* __restrict__ Ux_w, const float* __restrict__ Ux_b,
    float* __restrict__ hw, float* __restrict__ huT)
{
    __shared__ float hs[32][34];   // stride 34: (2r+kk)%32 -> worst 2-way (free)
    __shared__ float ws_[32][34];
    const int tx = threadIdx.x, ty = threadIdx.y;     // 16 x 16
    const int tl = ty * 16 + tx;
    const int row0 = blockIdx.y * 32;                 // 24 tiles over 768 rows
    const int col0 = blockIdx.x * 32;                 // 16 tiles over 512 cols

    float acc00 = 0.f, acc01 = 0.f, acc10 = 0.f, acc11 = 0.f;

    for (int k0 = 0; k0 < HDIM; k0 += 32) {
        {
            const int r  = tl / 8;          // 0..31
            const int kk = (tl % 8) * 4;    // 0,4,...,28
            const float4 hv = *(const float4*)&h[(row0 + r) * HDIM + k0 + kk];
            hs[r][kk]   = hv.x; hs[r][kk+1] = hv.y;
            hs[r][kk+2] = hv.z; hs[r][kk+3] = hv.w;
            const int c = col0 + r;
            const float* Wrow = (c < HDIM) ? &Wx_w[c * HDIM] : &Ux_w[(c - HDIM) * HDIM];
            const float4 wv = *(const float4*)&Wrow[k0 + kk];
            ws_[r][kk]   = wv.x; ws_[r][kk+1] = wv.y;
            ws_[r][kk+2] = wv.z; ws_[r][kk+3] = wv.w;
        }
        __syncthreads();
        #pragma unroll
        for (int kk = 0; kk < 32; ++kk) {
            const float a0 = hs[ty*2][kk],  a1 = hs[ty*2+1][kk];
            const float b0 = ws_[tx*2][kk], b1 = ws_[tx*2+1][kk];
            acc00 = fmaf(a0, b0, acc00); acc01 = fmaf(a0, b1, acc01);
            acc10 = fmaf(a1, b0, acc10); acc11 = fmaf(a1, b1, acc11);
        }
        __syncthreads();
    }

    float accs[2][2] = {{acc00, acc01}, {acc10, acc11}};
    #pragma unroll
    for (int dy = 0; dy < 2; ++dy) {
        const int row = row0 + ty * 2 + dy;
        const int b = row / LDIM, i = row % LDIM;
        #pragma unroll
        for (int dx = 0; dx < 2; ++dx) {
            const int c = col0 + tx * 2 + dx;
            float v = accs[dy][dx];
            if (c < HDIM) {
                v += Wx_b[c];
                hw[row * HDIM + c] = v;
            } else {
                const int ch = c - HDIM;
                v += Ux_b[ch];
                huT[(b * HDIM + ch) * LDIM + i] = v;
            }
        }
    }
}

// ---------------------------------------------------------------------------
// Kernel 2: one block per (b,i); thread j computes gate[b,i,j,:]; j-reduction
// via LDS. hw/Tx_w reads are wave-uniform -> scalarized by the compiler.
// ---------------------------------------------------------------------------
__global__ __launch_bounds__(384) void k_main(
    const float* __restrict__ hw, const float* __restrict__ huT,
    const float* __restrict__ X, const int* __restrict__ mask,
    const float* __restrict__ Tx_w, const float* __restrict__ Tx_b,
    float* __restrict__ out)
{
    __shared__ float G[LDIM][16];     // [j][a] = gate*m  (a=14: m), a=15 unused
    __shared__ float part[57][8];
    __shared__ float red[57];

    const int i = blockIdx.x;         // 0..383
    const int b = blockIdx.y;         // 0..1
    const int j = threadIdx.x;        // 0..383

    const float m = (float)mask[b * LDIM + j];
    const float* __restrict__ hwrow = &hw[(b * LDIM + i) * HDIM];   // uniform
    const float* __restrict__ hub   = &huT[b * HDIM * LDIM + j];    // lane-coalesced

    float g[ADIM];
    #pragma unroll
    for (int a = 0; a < ADIM; ++a) g[a] = Tx_b[a];

    #pragma unroll 4
    for (int hh = 0; hh < HDIM; ++hh) {
        const float uv = hub[hh * LDIM];
        float t = hwrow[hh] + uv;       // hwrow[hh]: s_load (uniform)
        t = fmaxf(t, 0.f);
        #pragma unroll
        for (int a = 0; a < ADIM; ++a)
            g[a] = fmaf(t, Tx_w[a * HDIM + hh], g[a]);  // Tx_w: s_load (uniform)
    }

    #pragma unroll
    for (int a = 0; a < ADIM; ++a) G[j][a] = g[a] * m;
    G[j][ADIM] = m;
    __syncthreads();

    // phase 2: 57 sums over j (42 S2 + 14 S1 + 1 msum), 6 segments of 64 each
    if (j < 342) {
        const int out_id = j / 6, seg = j % 6;
        const int j0 = seg * 64;
        float p = 0.f;
        if (out_id < 42) {
            const int a = out_id / 3, c = out_id % 3;
            const float* Xb = &X[((b * LDIM) * ADIM + a) * 3 + c];
            #pragma unroll 4
            for (int jj = 0; jj < 64; ++jj)
                p += G[j0 + jj][a] * Xb[(j0 + jj) * (ADIM * 3)];
        } else if (out_id < 56) {
            const int a = out_id - 42;
            #pragma unroll 4
            for (int jj = 0; jj < 64; ++jj) p += G[j0 + jj][a];
        } else {
            #pragma unroll 4
            for (int jj = 0; jj < 64; ++jj) p += G[j0 + jj][ADIM];
        }
        part[out_id][seg] = p;
    }
    __syncthreads();

    if (j < 57) {
        float s = 0.f;
        #pragma unroll
        for (int seg = 0; seg < 6; ++seg) s += part[j][seg];
        red[j] = s;
    }
    __syncthreads();

    if (j < 42) {
        const int a = j / 3, c = j % 3;
        const float denom = 1e-6f + red[56];
        const float S1 = red[42 + a];
        const float S2 = red[j];
        const int idx = ((b * LDIM + i) * ADIM + a) * 3 + c;
        const float xi = X[idx];
        float f = (xi * S1 - S2) / denom;
        f = fminf(fmaxf(f, -20.f), 20.f);
        out[idx] = xi + f;
    }
}

extern "C" void kernel_launch(void* const* d_in, const int* in_sizes, int n_in,
                              void* d_out, int out_size, void* d_ws, size_t ws_size,
                              hipStream_t stream) {
    (void)in_sizes; (void)n_in; (void)out_size; (void)ws_size;
    const float* h    = (const float*)d_in[0];
    const float* X    = (const float*)d_in[1];
    const int*   mask = (const int*)  d_in[2];
    const float* Wx_w = (const float*)d_in[3];
    const float* Wx_b = (const float*)d_in[4];
    const float* Ux_w = (const float*)d_in[5];
    const float* Ux_b = (const float*)d_in[6];
    const float* Tx_w = (const float*)d_in[7];
    const float* Tx_b = (const float*)d_in[8];
    float* out = (float*)d_out;

    float* hw  = (float*)d_ws;                 // B*L*H floats
    float* huT = hw + BDIM * LDIM * HDIM;      // B*H*L floats

    k_gemm<<<dim3(16, 24), dim3(16, 16), 0, stream>>>(h, Wx_w, Wx_b, Ux_w, Ux_b, hw, huT);
    k_main<<<dim3(LDIM, BDIM), 384, 0, stream>>>(hw, huT, X, mask, Tx_w, Tx_b, out);
}